// Round 1
// baseline (154.825 us; speedup 1.0000x reference)
//
#include <hip/hip_runtime.h>
#include <hip/hip_bf16.h>

#define NPAIR 4096
#define DIM   768
#define N2    8192
#define BM    64
#define BN    32
#define COLSPLIT 4
#define COLS_PER (N2 / COLSPLIT)       // 2048
#define KSTEPS (DIM / 32)              // 24
#define GRAN_PER_COL (DIM / 8)         // 96 granules of 8 bf16 (16B)
#define CHUNKS_PER_WAVE ((BN * GRAN_PER_COL) / 64 / 4)  // 12

constexpr float INV_T = 1.0f / 0.07f;  // also the fixed softmax max M

typedef __bf16 bf16x8 __attribute__((ext_vector_type(8)));
typedef float  f32x4  __attribute__((ext_vector_type(4)));

__device__ inline unsigned short f2bf(float x) {
    return __builtin_bit_cast(unsigned short, (__bf16)x);
}

// ---------------- normalize: one wave per row, fp32 in -> bf16 out ----------
__global__ void knorm(const float* __restrict__ z1, const float* __restrict__ z2,
                      unsigned short* __restrict__ zb) {
    const int row  = blockIdx.x * 4 + (threadIdx.x >> 6);
    const int lane = threadIdx.x & 63;
    const float* src = (row < NPAIR) ? (z1 + (size_t)row * DIM)
                                     : (z2 + (size_t)(row - NPAIR) * DIM);
    float4 v[3];
    float ss = 0.f;
#pragma unroll
    for (int i = 0; i < 3; ++i) {
        v[i] = reinterpret_cast<const float4*>(src)[lane + 64 * i];
        ss += v[i].x * v[i].x + v[i].y * v[i].y + v[i].z * v[i].z + v[i].w * v[i].w;
    }
#pragma unroll
    for (int off = 32; off; off >>= 1) ss += __shfl_xor(ss, off);
    const float scale = 1.0f / fmaxf(sqrtf(ss), 1e-12f);
    ushort4* dst = reinterpret_cast<ushort4*>(zb + (size_t)row * DIM);
#pragma unroll
    for (int i = 0; i < 3; ++i) {
        ushort4 o;
        o.x = f2bf(v[i].x * scale); o.y = f2bf(v[i].y * scale);
        o.z = f2bf(v[i].z * scale); o.w = f2bf(v[i].w * scale);
        dst[lane + 64 * i] = o;
    }
}

// ---------------- positive-pair dots: one wave per pair ---------------------
__global__ void kpos(const unsigned short* __restrict__ zb, float* __restrict__ pos) {
    const int pair = blockIdx.x * 4 + (threadIdx.x >> 6);
    const int lane = threadIdx.x & 63;
    const bf16x8* a = reinterpret_cast<const bf16x8*>(zb + (size_t)pair * DIM);
    const bf16x8* b = reinterpret_cast<const bf16x8*>(zb + (size_t)(pair + NPAIR) * DIM);
    float s = 0.f;
#pragma unroll
    for (int c = 0; c < 2; ++c) {
        const int idx = lane + 64 * c;
        if (idx < GRAN_PER_COL) {
            bf16x8 va = a[idx], vb = b[idx];
#pragma unroll
            for (int j = 0; j < 8; ++j) s += (float)va[j] * (float)vb[j];
        }
    }
#pragma unroll
    for (int off = 32; off; off >>= 1) s += __shfl_xor(s, off);
    if (lane == 0) pos[pair] = s * INV_T;
}

// ---------------- main: row-sums of exp(sim - M), diag masked ---------------
// 4 waves x 16 rows = BM=64 rows/block; Q in registers (24 x bf16x8);
// B tile of 32 cols staged in 48KB LDS via global_load_lds (source-swizzled).
__global__ __launch_bounds__(256) void klse(const unsigned short* __restrict__ zb,
                                            float* __restrict__ rowsum) {
    __shared__ __align__(16) unsigned short Bs[BN * DIM];  // 48 KB
    const int wave = threadIdx.x >> 6;
    const int lane = threadIdx.x & 63;
    const int row0 = blockIdx.x * BM + wave * 16;
    const int cbase = blockIdx.y * COLS_PER;

    // Q fragments for this wave's 16 rows, entire K=768 (96 VGPRs)
    bf16x8 qf[KSTEPS];
    {
        const unsigned short* p = zb + (size_t)(row0 + (lane & 15)) * DIM + ((lane >> 4) << 3);
#pragma unroll
        for (int t = 0; t < KSTEPS; ++t)
            qf[t] = *reinterpret_cast<const bf16x8*>(p + t * 32);
    }

    float psum[4] = {0.f, 0.f, 0.f, 0.f};

    for (int ct = 0; ct < COLS_PER / BN; ++ct) {
        const int c0 = cbase + ct * BN;
        __syncthreads();  // previous tile's reads complete before overwrite
        // stage BN x DIM bf16; LDS linear, global source pre-XOR-swizzled
#pragma unroll
        for (int i = 0; i < CHUNKS_PER_WAVE; ++i) {
            const int chunk = wave * CHUNKS_PER_WAVE + i;
            const int g   = chunk * 64 + lane;          // 16B granule index
            const int col = g / GRAN_PER_COL;
            const int ko  = g - col * GRAN_PER_COL;
            const unsigned short* gsrc =
                zb + (size_t)(c0 + col) * DIM + ((ko ^ (col & 7)) << 3);
            __builtin_amdgcn_global_load_lds(
                (const __attribute__((address_space(1))) unsigned int*)gsrc,
                (__attribute__((address_space(3))) unsigned int*)(Bs + chunk * 512),
                16, 0, 0);
        }
        __syncthreads();

        f32x4 acc0 = {0.f, 0.f, 0.f, 0.f};
        f32x4 acc1 = {0.f, 0.f, 0.f, 0.f};
        const int cl0 = lane & 15, cl1 = cl0 + 16;
        const int kg  = lane >> 4;
#pragma unroll
        for (int t = 0; t < KSTEPS; ++t) {
            const int kk = t * 4 + kg;
            bf16x8 b0 = *reinterpret_cast<const bf16x8*>(
                &Bs[cl0 * DIM + ((kk ^ (cl0 & 7)) << 3)]);
            bf16x8 b1 = *reinterpret_cast<const bf16x8*>(
                &Bs[cl1 * DIM + ((kk ^ (cl1 & 7)) << 3)]);
            acc0 = __builtin_amdgcn_mfma_f32_16x16x32_bf16(qf[t], b0, acc0, 0, 0, 0);
            acc1 = __builtin_amdgcn_mfma_f32_16x16x32_bf16(qf[t], b1, acc1, 0, 0, 0);
        }

        const int colA = c0 + cl0, colB = c0 + cl1;
        const int rbase = row0 + (kg << 2);
#pragma unroll
        for (int r = 0; r < 4; ++r) {
            const int row = rbase + r;
            float e0 = __expf((acc0[r] - 1.0f) * INV_T);
            float e1 = __expf((acc1[r] - 1.0f) * INV_T);
            if (row == colA) e0 = 0.f;   // mask diagonal
            if (row == colB) e1 = 0.f;
            psum[r] += e0 + e1;
        }
    }

    // reduce across the 16 lanes sharing each row group, then atomics
#pragma unroll
    for (int r = 0; r < 4; ++r)
#pragma unroll
        for (int m = 1; m < 16; m <<= 1)
            psum[r] += __shfl_xor(psum[r], m);
    if ((lane & 15) == 0) {
        const int rbase = row0 + ((lane >> 4) << 2);
#pragma unroll
        for (int r = 0; r < 4; ++r)
            atomicAdd(&rowsum[rbase + r], psum[r]);
    }
}

// ---------------- final: loss = mean(M + log S_i - pos) ---------------------
__global__ void kfinal(const float* __restrict__ rowsum, const float* __restrict__ pos,
                       float* __restrict__ out) {
    __shared__ float red[8];
    const int tid = threadIdx.x;
    float s = 0.f;
    for (int i = tid; i < N2; i += 512) {
        const int p = (i < NPAIR) ? i : i - NPAIR;
        s += INV_T + __logf(rowsum[i]) - pos[p];
    }
#pragma unroll
    for (int off = 32; off; off >>= 1) s += __shfl_xor(s, off);
    if ((tid & 63) == 0) red[tid >> 6] = s;
    __syncthreads();
    if (tid == 0) {
        float t = 0.f;
#pragma unroll
        for (int w = 0; w < 8; ++w) t += red[w];
        out[0] = t / (float)N2;
    }
}

extern "C" void kernel_launch(void* const* d_in, const int* in_sizes, int n_in,
                              void* d_out, int out_size, void* d_ws, size_t ws_size,
                              hipStream_t stream) {
    const float* z1 = (const float*)d_in[0];
    const float* z2 = (const float*)d_in[1];
    unsigned short* zb = (unsigned short*)d_ws;                       // 8192*768 bf16
    float* rowsum = (float*)((char*)d_ws + (size_t)N2 * DIM * 2);     // 8192 f32
    float* pos = rowsum + N2;                                         // 4096 f32
    float* out = (float*)d_out;

    hipLaunchKernelGGL(knorm, dim3(N2 / 4), dim3(256), 0, stream, z1, z2, zb);
    hipLaunchKernelGGL(kpos, dim3(NPAIR / 4), dim3(256), 0, stream, zb, pos);
    hipMemsetAsync(rowsum, 0, N2 * sizeof(float), stream);
    hipLaunchKernelGGL(klse, dim3(N2 / BM, COLSPLIT), dim3(256), 0, stream, zb, rowsum);
    hipLaunchKernelGGL(kfinal, dim3(1), dim3(512), 0, stream, rowsum, pos, out);
}